// Round 8
// baseline (165.196 us; speedup 1.0000x reference)
//
#include <hip/hip_runtime.h>
#include <stdint.h>

#define B_SZ 2
#define T_SZ 2048
#define DMODEL 1024
#define HCNT 16
#define HD 64
#define MROWS (B_SZ * T_SZ)  // 4096

typedef __attribute__((ext_vector_type(8))) __bf16 bf16x8;
typedef __attribute__((ext_vector_type(4))) __bf16 bf16x4;
typedef __attribute__((ext_vector_type(4))) float f32x4;
typedef __attribute__((ext_vector_type(8))) unsigned short u16x8;

__device__ __forceinline__ unsigned short f2bf(float f) {
  union { float f; uint32_t u; } v; v.f = f;
  uint32_t u = v.u;
  u += 0x7fffu + ((u >> 16) & 1u);
  return (unsigned short)(u >> 16);
}

__device__ __forceinline__ float fexp2(float x) {
#if __has_builtin(__builtin_amdgcn_exp2f)
  return __builtin_amdgcn_exp2f(x);
#else
  return exp2f(x);
#endif
}

__device__ __forceinline__ void gld_lds16(const void* g, void* l) {
  __builtin_amdgcn_global_load_lds((__attribute__((address_space(1))) void*)(uintptr_t)g,
                                   (__attribute__((address_space(3))) void*)l, 16, 0, 0);
}

// ---------------- fp32 -> bf16 convert (both weight tensors, one launch) ----
__global__ __launch_bounds__(256)
void cvt_all(const float* __restrict__ qkv_w, const float* __restrict__ out_w,
             unsigned short* __restrict__ dst) {
  int i = blockIdx.x * 256 + threadIdx.x;
  const int n1 = 3 * DMODEL * DMODEL / 4;
  float4 v = (i < n1) ? ((const float4*)qkv_w)[i] : ((const float4*)out_w)[i - n1];
  ushort4 o;
  o.x = f2bf(v.x); o.y = f2bf(v.y); o.z = f2bf(v.z); o.w = f2bf(v.w);
  ((ushort4*)dst)[i] = o;
}

// ---------------- RMSNorm (fp32 in, bf16 out) ----------------
__global__ __launch_bounds__(256)
void rmsnorm_bf16(const float* __restrict__ x, const float* __restrict__ w,
                  unsigned short* __restrict__ xn) {
  const int row = blockIdx.x;
  const int t = threadIdx.x;
  float4 v = ((const float4*)(x + (size_t)row * DMODEL))[t];
  float ss = v.x * v.x + v.y * v.y + v.z * v.z + v.w * v.w;
#pragma unroll
  for (int o = 1; o < 64; o <<= 1) ss += __shfl_xor(ss, o, 64);
  __shared__ float red[4];
  if ((t & 63) == 0) red[t >> 6] = ss;
  __syncthreads();
  float tot = red[0] + red[1] + red[2] + red[3];
  float scale = rsqrtf(tot * (1.0f / (float)DMODEL) + 1e-6f);
  float4 wv = ((const float4*)w)[t];
  ushort4 o;
  o.x = f2bf(v.x * scale * wv.x);
  o.y = f2bf(v.y * scale * wv.y);
  o.z = f2bf(v.z * scale * wv.z);
  o.w = f2bf(v.w * scale * wv.w);
  ((ushort4*)(xn + (size_t)row * DMODEL))[t] = o;
}

// ---------------- bf16 NT GEMM: C[M][N] = A[M][K] * B[N][K]^T, BK=64 --------
// T2 XOR-swizzle (source pre-swizzled, LDS linear, read XORs the same).
__device__ __forceinline__ void stage128x64(const unsigned short* g, int ldg,
                                            unsigned short* lds, int tid) {
  const int wave = tid >> 6;
#pragma unroll
  for (int i = 0; i < 4; ++i) {
    int row = i * 32 + (tid >> 3);
    const unsigned short* gp = g + (size_t)row * ldg + (((tid & 7) ^ (row & 7)) << 3);
    gld_lds16(gp, lds + i * 2048 + wave * 512);
  }
}

template <int F32OUT>
__global__ __launch_bounds__(256, 2)
void gemm_bt(const unsigned short* __restrict__ A, const unsigned short* __restrict__ B,
             void* __restrict__ Cv, int M, int N, int K, int nbx) {
  __shared__ __align__(16) unsigned short As[2][128 * 64];
  __shared__ __align__(16) unsigned short Bs[2][128 * 64];
  const int t = threadIdx.x, wave = t >> 6, lane = t & 63;
  const int cpx = gridDim.x >> 3;
  const int swz = (blockIdx.x & 7) * cpx + (blockIdx.x >> 3);
  const int m0 = (swz / nbx) * 128, n0 = (swz % nbx) * 128;
  const int wr = wave >> 1, wc = wave & 1;
  const int c = lane & 15, qg = lane >> 4;
  f32x4 acc[4][4] = {};
  const int nk = K >> 6;
  stage128x64(A + (size_t)m0 * K, K, As[0], t);
  stage128x64(B + (size_t)n0 * K, K, Bs[0], t);
  __syncthreads();
  int buf = 0;
  for (int kt = 0; kt < nk; ++kt) {
    if (kt + 1 < nk) {
      stage128x64(A + (size_t)m0 * K + (kt + 1) * 64, K, As[buf ^ 1], t);
      stage128x64(B + (size_t)n0 * K + (kt + 1) * 64, K, Bs[buf ^ 1], t);
    }
#pragma unroll
    for (int kk = 0; kk < 2; ++kk) {
      bf16x8 af[4], bfr[4];
#pragma unroll
      for (int mi = 0; mi < 4; ++mi) {
        int row = wr * 64 + mi * 16 + c;
        af[mi] = *(const bf16x8*)&As[buf][row * 64 + (((kk * 4 + qg) ^ (row & 7)) << 3)];
      }
#pragma unroll
      for (int ni = 0; ni < 4; ++ni) {
        int row = wc * 64 + ni * 16 + c;
        bfr[ni] = *(const bf16x8*)&Bs[buf][row * 64 + (((kk * 4 + qg) ^ (row & 7)) << 3)];
      }
#pragma unroll
      for (int mi = 0; mi < 4; ++mi)
#pragma unroll
        for (int ni = 0; ni < 4; ++ni)
          acc[mi][ni] = __builtin_amdgcn_mfma_f32_16x16x32_bf16(af[mi], bfr[ni], acc[mi][ni], 0, 0, 0);
    }
    __syncthreads();
    buf ^= 1;
  }
  const int cr = qg * 4;
#pragma unroll
  for (int mi = 0; mi < 4; ++mi)
#pragma unroll
    for (int ni = 0; ni < 4; ++ni) {
      int row = m0 + wr * 64 + mi * 16 + cr;
      int col = n0 + wc * 64 + ni * 16 + c;
      if (F32OUT) {
        float* C = (float*)Cv;
#pragma unroll
        for (int r = 0; r < 4; ++r) C[(size_t)(row + r) * N + col] = acc[mi][ni][r];
      } else {
        unsigned short* C = (unsigned short*)Cv;
#pragma unroll
        for (int r = 0; r < 4; ++r) C[(size_t)(row + r) * N + col] = f2bf(acc[mi][ni][r]);
      }
    }
}

// ---------------- causal flash attention v7: K-from-L2, high occupancy ------
// 1024 blocks x 256 threads (4 waves x 16 q-rows = 64-row q-tile), KVBLK=128.
// K fragments read DIRECTLY from global (L2-resident after XCD pinning: 4 bh
// x 512KB = 2MB per 4MB XCD L2) -> no K LDS, no K-staging barrier. Only V is
// LDS-transposed (single buffer, reg-staged T14). LDS 35.8KB -> 4 blocks/CU;
// target VGPR <=128 -> 16 waves/CU in 4 independent barrier groups.
// Static balance: tile map (rank,f) makes every co-scheduled family of 4
// blocks sum to exactly 34 k-iters.
__global__ __launch_bounds__(256, 4)
void attn_causal(const unsigned short* __restrict__ qkv, unsigned short* __restrict__ ctx) {
  __shared__ __align__(16) unsigned short Vt[2][64 * 72];   // 18.4 KB (k-chunk 0/1)
  __shared__ __align__(16) unsigned short Pl[4][16 * 136];  // 17.4 KB (per-wave P)
  const int tid = threadIdx.x, wave = tid >> 6, lane = tid & 63;
  const int id = blockIdx.x;
  const int bh = id & 31;                   // id%8 = bh%8 -> all tiles of bh on one XCD
  const int ts = id >> 5;                   // 0..31
  const int f = ts & 7, rank = ts >> 3;
  const int qt = (rank == 0) ? (31 - f) : (rank == 1) ? f : (rank == 2) ? (16 + f) : (15 - f);
  const int b = bh >> 4, h = bh & 15;
  const int q0 = qt * 64 + wave * 16;       // this wave's 16 q-rows
  const int nit = (qt >> 1) + 1;
  const int c = lane & 15, qg = lane >> 4;
  const size_t base = (size_t)b * T_SZ * 3 * DMODEL;
  const unsigned short* Kg = qkv + base + DMODEL + h * HD;      // K base
  const unsigned short* Vg = qkv + base + 2 * DMODEL + h * HD;  // V base

  // Q fragments, pre-scaled by 0.125 * log2(e)
  const float QSC = 0.125f * 1.4426950408889634f;
  bf16x8 aq[2];
#pragma unroll
  for (int kk = 0; kk < 2; ++kk) {
    bf16x8 q = *(const bf16x8*)(qkv + base + (size_t)(q0 + c) * 3 * DMODEL + h * HD + kk * 32 + qg * 8);
#pragma unroll
    for (int j = 0; j < 8; ++j) q[j] = (__bf16)((float)q[j] * QSC);
    aq[kk] = q;
  }

  float mst = -3e38f, lst = 0.f;
  f32x4 aco[4];
#pragma unroll
  for (int nd = 0; nd < 4; ++nd)
#pragma unroll
    for (int r = 0; r < 4; ++r) aco[nd][r] = 0.f;

  auto loadV = [&](int kb, u16x8* v) {
#pragma unroll
    for (int i = 0; i < 4; ++i)
      v[i] = *(const u16x8*)(Vg + (size_t)(kb + i * 32 + (tid >> 3)) * 3 * DMODEL + (tid & 7) * 8);
  };
  auto writeV = [&](const u16x8* v) {
#pragma unroll
    for (int i = 0; i < 4; ++i) {
      int ch = i >> 1;
      int kv = (i & 1) * 32 + (tid >> 3);
#pragma unroll
      for (int j = 0; j < 8; ++j) {
        int dd = (tid & 7) * 8 + j;
        int ff = (tid & 7) ^ j;      // ((dd>>3)^dd)&7
        Vt[ch][dd * 72 + ((((kv >> 3) ^ ff) << 3) | (kv & 7))] = v[i][j];
      }
    }
  };

  auto computeTile = [&](int kb, bool domask) {
    // S^T = K Q^T : s[ni], k-row = kb + 16ni + 4qg + r, q-col = q0 + c
    f32x4 s[8] = {};
    __builtin_amdgcn_s_setprio(1);
#pragma unroll
    for (int kk = 0; kk < 2; ++kk) {
      bf16x8 bk[8];
#pragma unroll
      for (int ni = 0; ni < 8; ++ni)
        bk[ni] = *(const bf16x8*)(Kg + (size_t)(kb + ni * 16 + c) * 3 * DMODEL + kk * 32 + qg * 8);
#pragma unroll
      for (int ni = 0; ni < 8; ++ni)
        s[ni] = __builtin_amdgcn_mfma_f32_16x16x32_bf16(bk[ni], aq[kk], s[ni], 0, 0, 0);
    }
    __builtin_amdgcn_s_setprio(0);
    if (domask) {
#pragma unroll
      for (int ni = 0; ni < 8; ++ni)
#pragma unroll
        for (int r = 0; r < 4; ++r) {
          int kg = kb + ni * 16 + qg * 4 + r;
          if (kg > q0 + c) s[ni][r] = -1e30f;
        }
    }
    // online softmax (log2 domain), defer-max; row q0+c stats are lane-local
    float rm = -3e38f;
#pragma unroll
    for (int ni = 0; ni < 8; ++ni)
#pragma unroll
      for (int r = 0; r < 4; ++r) rm = fmaxf(rm, s[ni][r]);
    rm = fmaxf(rm, __shfl_xor(rm, 16, 64));
    rm = fmaxf(rm, __shfl_xor(rm, 32, 64));
    float mo = mst, mn = mo;
    if (__any(rm > mo + 11.5f)) {
      mn = fmaxf(mo, rm);
      float corr = fexp2(mo - mn);
      lst *= corr;
      mst = mn;
#pragma unroll
      for (int r = 0; r < 4; ++r) {
        float cr = __shfl(corr, qg * 20 + r, 64);   // corr of row 4qg+r
#pragma unroll
        for (int nd = 0; nd < 4; ++nd) aco[nd][r] *= cr;
      }
    }
    float rs = 0.f;
#pragma unroll
    for (int ni = 0; ni < 8; ++ni)
#pragma unroll
      for (int r = 0; r < 4; ++r) {
        float pv = fexp2(s[ni][r] - mn);
        s[ni][r] = pv;
        rs += pv;
      }
    rs += __shfl_xor(rs, 16, 64);
    rs += __shfl_xor(rs, 32, 64);
    lst += rs;
    // P -> per-wave LDS (b64 stores)
    unsigned short* P = Pl[wave];
#pragma unroll
    for (int ni = 0; ni < 8; ++ni) {
      bf16x4 pk;
#pragma unroll
      for (int r = 0; r < 4; ++r) pk[r] = (__bf16)s[ni][r];
      *(bf16x4*)&P[c * 136 + ni * 16 + qg * 4] = pk;
    }
    // PV: O += P[16x128] * V[128x64]
    __builtin_amdgcn_s_setprio(1);
#pragma unroll
    for (int ch = 0; ch < 2; ++ch)
#pragma unroll
      for (int kk = 0; kk < 2; ++kk) {
        bf16x8 bv[4];
#pragma unroll
        for (int nd = 0; nd < 4; ++nd) {
          int dd = nd * 16 + c;
          int ff = ((dd >> 3) ^ dd) & 7;
          int crd = kk * 4 + qg;
          bv[nd] = *(const bf16x8*)&Vt[ch][dd * 72 + ((crd ^ ff) << 3)];
        }
        bf16x8 pa = *(const bf16x8*)&P[c * 136 + ch * 64 + kk * 32 + qg * 8];
#pragma unroll
        for (int nd = 0; nd < 4; ++nd)
          aco[nd] = __builtin_amdgcn_mfma_f32_16x16x32_bf16(pa, bv[nd], aco[nd], 0, 0, 0);
      }
    __builtin_amdgcn_s_setprio(0);
  };

  // prologue: V tile 0
  u16x8 vn[4];
  loadV(0, vn);
  writeV(vn);
  __syncthreads();
  for (int t = 0; t < nit; ++t) {
    const int kb = t * 128;
    const bool hn = (t + 1 < nit);
    if (hn) loadV(kb + 128, vn);         // T14: issue early, hide under compute
    computeTile(kb, t == nit - 1);
    if (hn) {
      __syncthreads();                   // all waves done reading Vt
      writeV(vn);
      __syncthreads();                   // Vt holds tile t+1
    }
  }

  // epilogue: O /= l  (row = q0 + 4qg + r)
  unsigned short* outp = ctx + (size_t)b * T_SZ * DMODEL + h * HD;
  float linv = 1.f / lst;
#pragma unroll
  for (int r = 0; r < 4; ++r) {
    float inv = __shfl(linv, qg * 20 + r, 64);
    int q = q0 + qg * 4 + r;
#pragma unroll
    for (int nd = 0; nd < 4; ++nd)
      outp[(size_t)q * DMODEL + nd * 16 + c] = f2bf(aco[nd][r] * inv);
  }
}

extern "C" void kernel_launch(void* const* d_in, const int* in_sizes, int n_in,
                              void* d_out, int out_size, void* d_ws, size_t ws_size,
                              hipStream_t stream) {
  const float* x = (const float*)d_in[0];
  const float* nw = (const float*)d_in[1];
  const float* qkv_w = (const float*)d_in[2];
  const float* out_w = (const float*)d_in[3];
  float* out = (float*)d_out;

  unsigned short* ws = (unsigned short*)d_ws;
  unsigned short* xn = ws;
  unsigned short* qkvw = xn + (size_t)MROWS * DMODEL;
  unsigned short* outw = qkvw + (size_t)3 * DMODEL * DMODEL;
  unsigned short* qkv = outw + (size_t)DMODEL * DMODEL;
  unsigned short* ctx = qkv + (size_t)MROWS * 3 * DMODEL;

  cvt_all<<<dim3(4096), dim3(256), 0, stream>>>(qkv_w, out_w, qkvw);
  rmsnorm_bf16<<<dim3(MROWS), dim3(256), 0, stream>>>(x, nw, xn);
  gemm_bt<0><<<dim3(768), dim3(256), 0, stream>>>(xn, qkvw, qkv, MROWS, 3 * DMODEL, DMODEL, 24);
  attn_causal<<<dim3(1024), dim3(256), 0, stream>>>(qkv, ctx);
  gemm_bt<1><<<dim3(256), dim3(256), 0, stream>>>(ctx, outw, out, MROWS, DMODEL, DMODEL, 8);
}

// Round 9
// 133.252 us; speedup vs baseline: 1.2397x; 1.2397x over previous
//
#include <hip/hip_runtime.h>
#include <stdint.h>

#define B_SZ 2
#define T_SZ 2048
#define DMODEL 1024
#define HCNT 16
#define HD 64
#define MROWS (B_SZ * T_SZ)  // 4096

typedef __attribute__((ext_vector_type(8))) __bf16 bf16x8;
typedef __attribute__((ext_vector_type(4))) __bf16 bf16x4;
typedef __attribute__((ext_vector_type(4))) float f32x4;
typedef __attribute__((ext_vector_type(8))) unsigned short u16x8;

__device__ __forceinline__ unsigned short f2bf(float f) {
  union { float f; uint32_t u; } v; v.f = f;
  uint32_t u = v.u;
  u += 0x7fffu + ((u >> 16) & 1u);
  return (unsigned short)(u >> 16);
}

__device__ __forceinline__ float fexp2(float x) {
#if __has_builtin(__builtin_amdgcn_exp2f)
  return __builtin_amdgcn_exp2f(x);
#else
  return exp2f(x);
#endif
}

__device__ __forceinline__ void gld_lds16(const void* g, void* l) {
  __builtin_amdgcn_global_load_lds((__attribute__((address_space(1))) void*)(uintptr_t)g,
                                   (__attribute__((address_space(3))) void*)l, 16, 0, 0);
}

// ---------------- fp32 -> bf16 convert (both weight tensors, one launch) ----
__global__ __launch_bounds__(256)
void cvt_all(const float* __restrict__ qkv_w, const float* __restrict__ out_w,
             unsigned short* __restrict__ dst) {
  int i = blockIdx.x * 256 + threadIdx.x;
  const int n1 = 3 * DMODEL * DMODEL / 4;
  float4 v = (i < n1) ? ((const float4*)qkv_w)[i] : ((const float4*)out_w)[i - n1];
  ushort4 o;
  o.x = f2bf(v.x); o.y = f2bf(v.y); o.z = f2bf(v.z); o.w = f2bf(v.w);
  ((ushort4*)dst)[i] = o;
}

// ---------------- RMSNorm (fp32 in, bf16 out) ----------------
__global__ __launch_bounds__(256)
void rmsnorm_bf16(const float* __restrict__ x, const float* __restrict__ w,
                  unsigned short* __restrict__ xn) {
  const int row = blockIdx.x;
  const int t = threadIdx.x;
  float4 v = ((const float4*)(x + (size_t)row * DMODEL))[t];
  float ss = v.x * v.x + v.y * v.y + v.z * v.z + v.w * v.w;
#pragma unroll
  for (int o = 1; o < 64; o <<= 1) ss += __shfl_xor(ss, o, 64);
  __shared__ float red[4];
  if ((t & 63) == 0) red[t >> 6] = ss;
  __syncthreads();
  float tot = red[0] + red[1] + red[2] + red[3];
  float scale = rsqrtf(tot * (1.0f / (float)DMODEL) + 1e-6f);
  float4 wv = ((const float4*)w)[t];
  ushort4 o;
  o.x = f2bf(v.x * scale * wv.x);
  o.y = f2bf(v.y * scale * wv.y);
  o.z = f2bf(v.z * scale * wv.z);
  o.w = f2bf(v.w * scale * wv.w);
  ((ushort4*)(xn + (size_t)row * DMODEL))[t] = o;
}

// ---------------- bf16 NT GEMM: C[M][N] = A[M][K] * B[N][K]^T, BK=64 --------
// T2 XOR-swizzle (source pre-swizzled, LDS linear, read XORs the same).
__device__ __forceinline__ void stage128x64(const unsigned short* g, int ldg,
                                            unsigned short* lds, int tid) {
  const int wave = tid >> 6;
#pragma unroll
  for (int i = 0; i < 4; ++i) {
    int row = i * 32 + (tid >> 3);
    const unsigned short* gp = g + (size_t)row * ldg + (((tid & 7) ^ (row & 7)) << 3);
    gld_lds16(gp, lds + i * 2048 + wave * 512);
  }
}

template <int F32OUT>
__global__ __launch_bounds__(256, 2)
void gemm_bt(const unsigned short* __restrict__ A, const unsigned short* __restrict__ B,
             void* __restrict__ Cv, int M, int N, int K, int nbx) {
  __shared__ __align__(16) unsigned short As[2][128 * 64];
  __shared__ __align__(16) unsigned short Bs[2][128 * 64];
  const int t = threadIdx.x, wave = t >> 6, lane = t & 63;
  const int cpx = gridDim.x >> 3;
  const int swz = (blockIdx.x & 7) * cpx + (blockIdx.x >> 3);
  const int m0 = (swz / nbx) * 128, n0 = (swz % nbx) * 128;
  const int wr = wave >> 1, wc = wave & 1;
  const int c = lane & 15, qg = lane >> 4;
  f32x4 acc[4][4] = {};
  const int nk = K >> 6;
  stage128x64(A + (size_t)m0 * K, K, As[0], t);
  stage128x64(B + (size_t)n0 * K, K, Bs[0], t);
  __syncthreads();
  int buf = 0;
  for (int kt = 0; kt < nk; ++kt) {
    if (kt + 1 < nk) {
      stage128x64(A + (size_t)m0 * K + (kt + 1) * 64, K, As[buf ^ 1], t);
      stage128x64(B + (size_t)n0 * K + (kt + 1) * 64, K, Bs[buf ^ 1], t);
    }
#pragma unroll
    for (int kk = 0; kk < 2; ++kk) {
      bf16x8 af[4], bfr[4];
#pragma unroll
      for (int mi = 0; mi < 4; ++mi) {
        int row = wr * 64 + mi * 16 + c;
        af[mi] = *(const bf16x8*)&As[buf][row * 64 + (((kk * 4 + qg) ^ (row & 7)) << 3)];
      }
#pragma unroll
      for (int ni = 0; ni < 4; ++ni) {
        int row = wc * 64 + ni * 16 + c;
        bfr[ni] = *(const bf16x8*)&Bs[buf][row * 64 + (((kk * 4 + qg) ^ (row & 7)) << 3)];
      }
#pragma unroll
      for (int mi = 0; mi < 4; ++mi)
#pragma unroll
        for (int ni = 0; ni < 4; ++ni)
          acc[mi][ni] = __builtin_amdgcn_mfma_f32_16x16x32_bf16(af[mi], bfr[ni], acc[mi][ni], 0, 0, 0);
    }
    __syncthreads();
    buf ^= 1;
  }
  const int cr = qg * 4;
#pragma unroll
  for (int mi = 0; mi < 4; ++mi)
#pragma unroll
    for (int ni = 0; ni < 4; ++ni) {
      int row = m0 + wr * 64 + mi * 16 + cr;
      int col = n0 + wc * 64 + ni * 16 + c;
      if (F32OUT) {
        float* C = (float*)Cv;
#pragma unroll
        for (int r = 0; r < 4; ++r) C[(size_t)(row + r) * N + col] = acc[mi][ni][r];
      } else {
        unsigned short* C = (unsigned short*)Cv;
#pragma unroll
        for (int r = 0; r < 4; ++r) C[(size_t)(row + r) * N + col] = f2bf(acc[mi][ni][r]);
      }
    }
}

// ---------------- causal flash attention v8: 16 waves/CU -------------------
// 1024 blocks x 256 thr (4 waves x 16 q-rows = 64-row tile), KVBLK=128.
// K LDS-staged via gld_lds (coalesced), single-buffered 16 KB; V single
// 18 KB (reg-staged T14); P per-wave 16x40 strip reused per (ch,kk) 5 KB.
// Total LDS 39.9 KB -> exactly 4 blocks/CU (all 1024 resident, 16 waves/CU).
// __launch_bounds__(256,4) caps VGPR at 128 (live set ~105, no spill).
// v7's sum-34 family map balances per-CU work; XCD pinned via id%8.
__global__ __launch_bounds__(256, 4)
void attn_causal(const unsigned short* __restrict__ qkv, unsigned short* __restrict__ ctx) {
  __shared__ __align__(16) unsigned short Ks[128 * 64];     // 16 KB single
  __shared__ __align__(16) unsigned short Vt[2][64 * 72];   // 18 KB single (2 ch)
  __shared__ __align__(16) unsigned short Pl[4][16 * 40];   // 5 KB (per-wave strip)
  const int tid = threadIdx.x, wave = tid >> 6, lane = tid & 63;
  const int id = blockIdx.x;
  const int bh = id & 31;                   // id%8 = bh%8 -> bh pinned to one XCD
  const int ts = id >> 5;                   // 0..31
  const int f = ts & 7, rank = ts >> 3;
  const int qt = (rank == 0) ? (31 - f) : (rank == 1) ? f : (rank == 2) ? (16 + f) : (15 - f);
  const int b = bh >> 4, h = bh & 15;
  const int q0 = qt * 64 + wave * 16;       // this wave's 16 q-rows
  const int nit = (qt >> 1) + 1;
  const int c = lane & 15, qg = lane >> 4;
  const size_t base = (size_t)b * T_SZ * 3 * DMODEL;
  const unsigned short* Kg = qkv + base + DMODEL + h * HD;
  const unsigned short* Vg = qkv + base + 2 * DMODEL + h * HD;

  // Q fragments, pre-scaled by 0.125 * log2(e)
  const float QSC = 0.125f * 1.4426950408889634f;
  bf16x8 aq[2];
#pragma unroll
  for (int kk = 0; kk < 2; ++kk) {
    bf16x8 q = *(const bf16x8*)(qkv + base + (size_t)(q0 + c) * 3 * DMODEL + h * HD + kk * 32 + qg * 8);
#pragma unroll
    for (int j = 0; j < 8; ++j) q[j] = (__bf16)((float)q[j] * QSC);
    aq[kk] = q;
  }

  float mst = -3e38f, lst = 0.f;
  f32x4 aco[4];
#pragma unroll
  for (int nd = 0; nd < 4; ++nd)
#pragma unroll
    for (int r = 0; r < 4; ++r) aco[nd][r] = 0.f;

  auto stageK = [&](int kb) {
#pragma unroll
    for (int i = 0; i < 4; ++i) {
      int row = i * 32 + (tid >> 3);
      gld_lds16(Kg + (size_t)(kb + row) * 3 * DMODEL + (((tid & 7) ^ (row & 7)) << 3),
                &Ks[i * 2048 + (wave << 9)]);
    }
  };
  auto loadV = [&](int kb, u16x8* v) {
#pragma unroll
    for (int i = 0; i < 4; ++i)
      v[i] = *(const u16x8*)(Vg + (size_t)(kb + i * 32 + (tid >> 3)) * 3 * DMODEL + (tid & 7) * 8);
  };
  auto writeV = [&](const u16x8* v) {
#pragma unroll
    for (int i = 0; i < 4; ++i) {
      int ch = i >> 1;
      int kv = (i & 1) * 32 + (tid >> 3);
#pragma unroll
      for (int j = 0; j < 8; ++j) {
        int dd = (tid & 7) * 8 + j;
        int ff = (tid & 7) ^ j;      // ((dd>>3)^dd)&7
        Vt[ch][dd * 72 + ((((kv >> 3) ^ ff) << 3) | (kv & 7))] = v[i][j];
      }
    }
  };

  u16x8 vn[4];

  auto computeTile = [&](int kb, bool domask, bool hn) {
    // S^T = K Q^T : s[ni], k-row = kb + 16ni + 4qg + r, q-col = q0 + c
    f32x4 s[8] = {};
    __builtin_amdgcn_s_setprio(1);
#pragma unroll
    for (int kk = 0; kk < 2; ++kk) {
      bf16x8 bk[8];
#pragma unroll
      for (int ni = 0; ni < 8; ++ni) {
        int row = ni * 16 + c;
        int crd = kk * 4 + qg;
        bk[ni] = *(const bf16x8*)&Ks[row * 64 + ((crd ^ (row & 7)) << 3)];
      }
#pragma unroll
      for (int ni = 0; ni < 8; ++ni)
        s[ni] = __builtin_amdgcn_mfma_f32_16x16x32_bf16(bk[ni], aq[kk], s[ni], 0, 0, 0);
    }
    __builtin_amdgcn_s_setprio(0);
    if (hn) loadV(kb + 128, vn);   // T14: HBM/L2 latency hidden under softmax+PV
    if (domask) {
#pragma unroll
      for (int ni = 0; ni < 8; ++ni)
#pragma unroll
        for (int r = 0; r < 4; ++r) {
          int kg = kb + ni * 16 + qg * 4 + r;
          if (kg > q0 + c) s[ni][r] = -1e30f;
        }
    }
    // online softmax (log2 domain), defer-max; row q0+c stats lane-local
    float rm = -3e38f;
#pragma unroll
    for (int ni = 0; ni < 8; ++ni)
#pragma unroll
      for (int r = 0; r < 4; ++r) rm = fmaxf(rm, s[ni][r]);
    rm = fmaxf(rm, __shfl_xor(rm, 16, 64));
    rm = fmaxf(rm, __shfl_xor(rm, 32, 64));
    float mo = mst, mn = mo;
    if (__any(rm > mo + 11.5f)) {
      mn = fmaxf(mo, rm);
      float corr = fexp2(mo - mn);
      lst *= corr;
      mst = mn;
#pragma unroll
      for (int r = 0; r < 4; ++r) {
        float cr = __shfl(corr, qg * 20 + r, 64);
#pragma unroll
        for (int nd = 0; nd < 4; ++nd) aco[nd][r] *= cr;
      }
    }
    float rs = 0.f;
#pragma unroll
    for (int ni = 0; ni < 8; ++ni)
#pragma unroll
      for (int r = 0; r < 4; ++r) {
        float pv = fexp2(s[ni][r] - mn);
        s[ni][r] = pv;
        rs += pv;
      }
    rs += __shfl_xor(rs, 16, 64);
    rs += __shfl_xor(rs, 32, 64);
    lst += rs;
    // PV per 32-col slice: write P strip, read pa + bv, 4 MFMA. P strip is
    // reused across slices; same-address write-after-read keeps DS in order.
    unsigned short* P = Pl[wave];
    __builtin_amdgcn_s_setprio(1);
#pragma unroll
    for (int ch = 0; ch < 2; ++ch)
#pragma unroll
      for (int kk = 0; kk < 2; ++kk) {
#pragma unroll
        for (int par = 0; par < 2; ++par) {
          int ni = ch * 4 + kk * 2 + par;
          bf16x4 pk;
#pragma unroll
          for (int r = 0; r < 4; ++r) pk[r] = (__bf16)s[ni][r];
          *(bf16x4*)&P[c * 40 + par * 16 + qg * 4] = pk;
        }
        bf16x8 pa = *(const bf16x8*)&P[c * 40 + qg * 8];
        bf16x8 bv[4];
#pragma unroll
        for (int nd = 0; nd < 4; ++nd) {
          int dd = nd * 16 + c;
          int ff = ((dd >> 3) ^ dd) & 7;
          int crd = kk * 4 + qg;
          bv[nd] = *(const bf16x8*)&Vt[ch][dd * 72 + ((crd ^ ff) << 3)];
        }
#pragma unroll
        for (int nd = 0; nd < 4; ++nd)
          aco[nd] = __builtin_amdgcn_mfma_f32_16x16x32_bf16(pa, bv[nd], aco[nd], 0, 0, 0);
      }
    __builtin_amdgcn_s_setprio(0);
  };

  // prologue: tile 0 (K via gld_lds + V reg->LDS; one barrier drains both)
  stageK(0);
  loadV(0, vn);
  writeV(vn);
  __syncthreads();
  for (int t = 0; t < nit; ++t) {
    const int kb = t * 128;
    const bool hn = (t + 1 < nit);
    computeTile(kb, t == nit - 1, hn);
    __syncthreads();               // all waves done reading Ks/Vt
    if (hn) { stageK(kb + 128); writeV(vn); }
    __syncthreads();               // staging visible
  }

  // epilogue: O /= l  (row = q0 + 4qg + r)
  unsigned short* outp = ctx + (size_t)b * T_SZ * DMODEL + h * HD;
  float linv = 1.f / lst;
#pragma unroll
  for (int r = 0; r < 4; ++r) {
    float inv = __shfl(linv, qg * 20 + r, 64);
    int q = q0 + qg * 4 + r;
#pragma unroll
    for (int nd = 0; nd < 4; ++nd)
      outp[(size_t)q * DMODEL + nd * 16 + c] = f2bf(aco[nd][r] * inv);
  }
}

extern "C" void kernel_launch(void* const* d_in, const int* in_sizes, int n_in,
                              void* d_out, int out_size, void* d_ws, size_t ws_size,
                              hipStream_t stream) {
  const float* x = (const float*)d_in[0];
  const float* nw = (const float*)d_in[1];
  const float* qkv_w = (const float*)d_in[2];
  const float* out_w = (const float*)d_in[3];
  float* out = (float*)d_out;

  unsigned short* ws = (unsigned short*)d_ws;
  unsigned short* xn = ws;
  unsigned short* qkvw = xn + (size_t)MROWS * DMODEL;
  unsigned short* outw = qkvw + (size_t)3 * DMODEL * DMODEL;
  unsigned short* qkv = outw + (size_t)DMODEL * DMODEL;
  unsigned short* ctx = qkv + (size_t)MROWS * 3 * DMODEL;

  cvt_all<<<dim3(4096), dim3(256), 0, stream>>>(qkv_w, out_w, qkvw);
  rmsnorm_bf16<<<dim3(MROWS), dim3(256), 0, stream>>>(x, nw, xn);
  gemm_bt<0><<<dim3(768), dim3(256), 0, stream>>>(xn, qkvw, qkv, MROWS, 3 * DMODEL, DMODEL, 24);
  attn_causal<<<dim3(1024), dim3(256), 0, stream>>>(qkv, ctx);
  gemm_bt<1><<<dim3(256), dim3(256), 0, stream>>>(ctx, outw, out, MROWS, DMODEL, DMODEL, 8);
}

// Round 10
// 133.185 us; speedup vs baseline: 1.2404x; 1.0005x over previous
//
#include <hip/hip_runtime.h>
#include <stdint.h>

#define B_SZ 2
#define T_SZ 2048
#define DMODEL 1024
#define HCNT 16
#define HD 64
#define MROWS (B_SZ * T_SZ)  // 4096

typedef __attribute__((ext_vector_type(8))) __bf16 bf16x8;
typedef __attribute__((ext_vector_type(4))) __bf16 bf16x4;
typedef __attribute__((ext_vector_type(4))) float f32x4;
typedef __attribute__((ext_vector_type(8))) unsigned short u16x8;

__device__ __forceinline__ unsigned short f2bf(float f) {
  union { float f; uint32_t u; } v; v.f = f;
  uint32_t u = v.u;
  u += 0x7fffu + ((u >> 16) & 1u);
  return (unsigned short)(u >> 16);
}

__device__ __forceinline__ float fexp2(float x) {
#if __has_builtin(__builtin_amdgcn_exp2f)
  return __builtin_amdgcn_exp2f(x);
#else
  return exp2f(x);
#endif
}

__device__ __forceinline__ void gld_lds16(const void* g, void* l) {
  __builtin_amdgcn_global_load_lds((__attribute__((address_space(1))) void*)(uintptr_t)g,
                                   (__attribute__((address_space(3))) void*)l, 16, 0, 0);
}

// ---------------- fp32 -> bf16 convert (both weight tensors, one launch) ----
__global__ __launch_bounds__(256)
void cvt_all(const float* __restrict__ qkv_w, const float* __restrict__ out_w,
             unsigned short* __restrict__ dst) {
  int i = blockIdx.x * 256 + threadIdx.x;
  const int n1 = 3 * DMODEL * DMODEL / 4;
  float4 v = (i < n1) ? ((const float4*)qkv_w)[i] : ((const float4*)out_w)[i - n1];
  ushort4 o;
  o.x = f2bf(v.x); o.y = f2bf(v.y); o.z = f2bf(v.z); o.w = f2bf(v.w);
  ((ushort4*)dst)[i] = o;
}

// ---------------- RMSNorm (fp32 in, bf16 out) ----------------
__global__ __launch_bounds__(256)
void rmsnorm_bf16(const float* __restrict__ x, const float* __restrict__ w,
                  unsigned short* __restrict__ xn) {
  const int row = blockIdx.x;
  const int t = threadIdx.x;
  float4 v = ((const float4*)(x + (size_t)row * DMODEL))[t];
  float ss = v.x * v.x + v.y * v.y + v.z * v.z + v.w * v.w;
#pragma unroll
  for (int o = 1; o < 64; o <<= 1) ss += __shfl_xor(ss, o, 64);
  __shared__ float red[4];
  if ((t & 63) == 0) red[t >> 6] = ss;
  __syncthreads();
  float tot = red[0] + red[1] + red[2] + red[3];
  float scale = rsqrtf(tot * (1.0f / (float)DMODEL) + 1e-6f);
  float4 wv = ((const float4*)w)[t];
  ushort4 o;
  o.x = f2bf(v.x * scale * wv.x);
  o.y = f2bf(v.y * scale * wv.y);
  o.z = f2bf(v.z * scale * wv.z);
  o.w = f2bf(v.w * scale * wv.w);
  ((ushort4*)(xn + (size_t)row * DMODEL))[t] = o;
}

// ---------------- bf16 NT GEMM: C[M][N] = A[M][K] * B[N][K]^T, BK=64 --------
// T2 XOR-swizzle (source pre-swizzled, LDS linear, read XORs the same).
__device__ __forceinline__ void stage128x64(const unsigned short* g, int ldg,
                                            unsigned short* lds, int tid) {
  const int wave = tid >> 6;
#pragma unroll
  for (int i = 0; i < 4; ++i) {
    int row = i * 32 + (tid >> 3);
    const unsigned short* gp = g + (size_t)row * ldg + (((tid & 7) ^ (row & 7)) << 3);
    gld_lds16(gp, lds + i * 2048 + wave * 512);
  }
}

template <int F32OUT>
__global__ __launch_bounds__(256, 2)
void gemm_bt(const unsigned short* __restrict__ A, const unsigned short* __restrict__ B,
             void* __restrict__ Cv, int M, int N, int K, int nbx) {
  __shared__ __align__(16) unsigned short As[2][128 * 64];
  __shared__ __align__(16) unsigned short Bs[2][128 * 64];
  const int t = threadIdx.x, wave = t >> 6, lane = t & 63;
  const int cpx = gridDim.x >> 3;
  const int swz = (blockIdx.x & 7) * cpx + (blockIdx.x >> 3);
  const int m0 = (swz / nbx) * 128, n0 = (swz % nbx) * 128;
  const int wr = wave >> 1, wc = wave & 1;
  const int c = lane & 15, qg = lane >> 4;
  f32x4 acc[4][4] = {};
  const int nk = K >> 6;
  stage128x64(A + (size_t)m0 * K, K, As[0], t);
  stage128x64(B + (size_t)n0 * K, K, Bs[0], t);
  __syncthreads();
  int buf = 0;
  for (int kt = 0; kt < nk; ++kt) {
    if (kt + 1 < nk) {
      stage128x64(A + (size_t)m0 * K + (kt + 1) * 64, K, As[buf ^ 1], t);
      stage128x64(B + (size_t)n0 * K + (kt + 1) * 64, K, Bs[buf ^ 1], t);
    }
#pragma unroll
    for (int kk = 0; kk < 2; ++kk) {
      bf16x8 af[4], bfr[4];
#pragma unroll
      for (int mi = 0; mi < 4; ++mi) {
        int row = wr * 64 + mi * 16 + c;
        af[mi] = *(const bf16x8*)&As[buf][row * 64 + (((kk * 4 + qg) ^ (row & 7)) << 3)];
      }
#pragma unroll
      for (int ni = 0; ni < 4; ++ni) {
        int row = wc * 64 + ni * 16 + c;
        bfr[ni] = *(const bf16x8*)&Bs[buf][row * 64 + (((kk * 4 + qg) ^ (row & 7)) << 3)];
      }
#pragma unroll
      for (int mi = 0; mi < 4; ++mi)
#pragma unroll
        for (int ni = 0; ni < 4; ++ni)
          acc[mi][ni] = __builtin_amdgcn_mfma_f32_16x16x32_bf16(af[mi], bfr[ni], acc[mi][ni], 0, 0, 0);
    }
    __syncthreads();
    buf ^= 1;
  }
  const int cr = qg * 4;
#pragma unroll
  for (int mi = 0; mi < 4; ++mi)
#pragma unroll
    for (int ni = 0; ni < 4; ++ni) {
      int row = m0 + wr * 64 + mi * 16 + cr;
      int col = n0 + wc * 64 + ni * 16 + c;
      if (F32OUT) {
        float* C = (float*)Cv;
#pragma unroll
        for (int r = 0; r < 4; ++r) C[(size_t)(row + r) * N + col] = acc[mi][ni][r];
      } else {
        unsigned short* C = (unsigned short*)Cv;
#pragma unroll
        for (int r = 0; r < 4; ++r) C[(size_t)(row + r) * N + col] = f2bf(acc[mi][ni][r]);
      }
    }
}

// ---------------- causal flash attention v9: v8 minus register throttle ----
// Identical structure to v8 (1024 blocks x 256 thr, KVBLK=128, K gld_lds
// single, V reg-staged T14, P-strip, 39.9 KB LDS -> 4 blocks/CU). The one
// change: amdgpu_waves_per_eu(4,4) pins occupancy at exactly 4 waves/EU so
// the allocator gets the full 128-VGPR budget (v8's launch_bounds(256,4) let
// the compiler over-throttle to 64 VGPR -> scratch spills, 21.5 MB writes).
__global__ __attribute__((amdgpu_flat_work_group_size(256, 256), amdgpu_waves_per_eu(4, 4)))
void attn_causal(const unsigned short* __restrict__ qkv, unsigned short* __restrict__ ctx) {
  __shared__ __align__(16) unsigned short Ks[128 * 64];     // 16 KB single
  __shared__ __align__(16) unsigned short Vt[2][64 * 72];   // 18 KB single (2 ch)
  __shared__ __align__(16) unsigned short Pl[4][16 * 40];   // 5 KB (per-wave strip)
  const int tid = threadIdx.x, wave = tid >> 6, lane = tid & 63;
  const int id = blockIdx.x;
  const int bh = id & 31;                   // id%8 = bh%8 -> bh pinned to one XCD
  const int ts = id >> 5;                   // 0..31
  const int f = ts & 7, rank = ts >> 3;
  const int qt = (rank == 0) ? (31 - f) : (rank == 1) ? f : (rank == 2) ? (16 + f) : (15 - f);
  const int b = bh >> 4, h = bh & 15;
  const int q0 = qt * 64 + wave * 16;       // this wave's 16 q-rows
  const int nit = (qt >> 1) + 1;
  const int c = lane & 15, qg = lane >> 4;
  const size_t base = (size_t)b * T_SZ * 3 * DMODEL;
  const unsigned short* Kg = qkv + base + DMODEL + h * HD;
  const unsigned short* Vg = qkv + base + 2 * DMODEL + h * HD;

  // Q fragments, pre-scaled by 0.125 * log2(e)
  const float QSC = 0.125f * 1.4426950408889634f;
  bf16x8 aq[2];
#pragma unroll
  for (int kk = 0; kk < 2; ++kk) {
    bf16x8 q = *(const bf16x8*)(qkv + base + (size_t)(q0 + c) * 3 * DMODEL + h * HD + kk * 32 + qg * 8);
#pragma unroll
    for (int j = 0; j < 8; ++j) q[j] = (__bf16)((float)q[j] * QSC);
    aq[kk] = q;
  }

  float mst = -3e38f, lst = 0.f;
  f32x4 aco[4];
#pragma unroll
  for (int nd = 0; nd < 4; ++nd)
#pragma unroll
    for (int r = 0; r < 4; ++r) aco[nd][r] = 0.f;

  auto stageK = [&](int kb) {
#pragma unroll
    for (int i = 0; i < 4; ++i) {
      int row = i * 32 + (tid >> 3);
      gld_lds16(Kg + (size_t)(kb + row) * 3 * DMODEL + (((tid & 7) ^ (row & 7)) << 3),
                &Ks[i * 2048 + (wave << 9)]);
    }
  };
  auto loadV = [&](int kb, u16x8* v) {
#pragma unroll
    for (int i = 0; i < 4; ++i)
      v[i] = *(const u16x8*)(Vg + (size_t)(kb + i * 32 + (tid >> 3)) * 3 * DMODEL + (tid & 7) * 8);
  };
  auto writeV = [&](const u16x8* v) {
#pragma unroll
    for (int i = 0; i < 4; ++i) {
      int ch = i >> 1;
      int kv = (i & 1) * 32 + (tid >> 3);
#pragma unroll
      for (int j = 0; j < 8; ++j) {
        int dd = (tid & 7) * 8 + j;
        int ff = (tid & 7) ^ j;      // ((dd>>3)^dd)&7
        Vt[ch][dd * 72 + ((((kv >> 3) ^ ff) << 3) | (kv & 7))] = v[i][j];
      }
    }
  };

  u16x8 vn[4];

  auto computeTile = [&](int kb, bool domask, bool hn) {
    // S^T = K Q^T : s[ni], k-row = kb + 16ni + 4qg + r, q-col = q0 + c
    f32x4 s[8] = {};
    __builtin_amdgcn_s_setprio(1);
#pragma unroll
    for (int kk = 0; kk < 2; ++kk) {
      bf16x8 bk[8];
#pragma unroll
      for (int ni = 0; ni < 8; ++ni) {
        int row = ni * 16 + c;
        int crd = kk * 4 + qg;
        bk[ni] = *(const bf16x8*)&Ks[row * 64 + ((crd ^ (row & 7)) << 3)];
      }
#pragma unroll
      for (int ni = 0; ni < 8; ++ni)
        s[ni] = __builtin_amdgcn_mfma_f32_16x16x32_bf16(bk[ni], aq[kk], s[ni], 0, 0, 0);
    }
    __builtin_amdgcn_s_setprio(0);
    if (hn) loadV(kb + 128, vn);   // T14: HBM/L2 latency hidden under softmax+PV
    if (domask) {
#pragma unroll
      for (int ni = 0; ni < 8; ++ni)
#pragma unroll
        for (int r = 0; r < 4; ++r) {
          int kg = kb + ni * 16 + qg * 4 + r;
          if (kg > q0 + c) s[ni][r] = -1e30f;
        }
    }
    // online softmax (log2 domain), defer-max; row q0+c stats lane-local
    float rm = -3e38f;
#pragma unroll
    for (int ni = 0; ni < 8; ++ni)
#pragma unroll
      for (int r = 0; r < 4; ++r) rm = fmaxf(rm, s[ni][r]);
    rm = fmaxf(rm, __shfl_xor(rm, 16, 64));
    rm = fmaxf(rm, __shfl_xor(rm, 32, 64));
    float mo = mst, mn = mo;
    if (__any(rm > mo + 11.5f)) {
      mn = fmaxf(mo, rm);
      float corr = fexp2(mo - mn);
      lst *= corr;
      mst = mn;
#pragma unroll
      for (int r = 0; r < 4; ++r) {
        float cr = __shfl(corr, qg * 20 + r, 64);
#pragma unroll
        for (int nd = 0; nd < 4; ++nd) aco[nd][r] *= cr;
      }
    }
    float rs = 0.f;
#pragma unroll
    for (int ni = 0; ni < 8; ++ni)
#pragma unroll
      for (int r = 0; r < 4; ++r) {
        float pv = fexp2(s[ni][r] - mn);
        s[ni][r] = pv;
        rs += pv;
      }
    rs += __shfl_xor(rs, 16, 64);
    rs += __shfl_xor(rs, 32, 64);
    lst += rs;
    // PV per 32-col slice: write P strip, read pa + bv, 4 MFMA. P strip is
    // reused across slices; same-address write-after-read keeps DS in order.
    unsigned short* P = Pl[wave];
    __builtin_amdgcn_s_setprio(1);
#pragma unroll
    for (int ch = 0; ch < 2; ++ch)
#pragma unroll
      for (int kk = 0; kk < 2; ++kk) {
#pragma unroll
        for (int par = 0; par < 2; ++par) {
          int ni = ch * 4 + kk * 2 + par;
          bf16x4 pk;
#pragma unroll
          for (int r = 0; r < 4; ++r) pk[r] = (__bf16)s[ni][r];
          *(bf16x4*)&P[c * 40 + par * 16 + qg * 4] = pk;
        }
        bf16x8 pa = *(const bf16x8*)&P[c * 40 + qg * 8];
        bf16x8 bv[4];
#pragma unroll
        for (int nd = 0; nd < 4; ++nd) {
          int dd = nd * 16 + c;
          int ff = ((dd >> 3) ^ dd) & 7;
          int crd = kk * 4 + qg;
          bv[nd] = *(const bf16x8*)&Vt[ch][dd * 72 + ((crd ^ ff) << 3)];
        }
#pragma unroll
        for (int nd = 0; nd < 4; ++nd)
          aco[nd] = __builtin_amdgcn_mfma_f32_16x16x32_bf16(pa, bv[nd], aco[nd], 0, 0, 0);
      }
    __builtin_amdgcn_s_setprio(0);
  };

  // prologue: tile 0 (K via gld_lds + V reg->LDS; one barrier drains both)
  stageK(0);
  loadV(0, vn);
  writeV(vn);
  __syncthreads();
  for (int t = 0; t < nit; ++t) {
    const int kb = t * 128;
    const bool hn = (t + 1 < nit);
    computeTile(kb, t == nit - 1, hn);
    __syncthreads();               // all waves done reading Ks/Vt
    if (hn) { stageK(kb + 128); writeV(vn); }
    __syncthreads();               // staging visible
  }

  // epilogue: O /= l  (row = q0 + 4qg + r)
  unsigned short* outp = ctx + (size_t)b * T_SZ * DMODEL + h * HD;
  float linv = 1.f / lst;
#pragma unroll
  for (int r = 0; r < 4; ++r) {
    float inv = __shfl(linv, qg * 20 + r, 64);
    int q = q0 + qg * 4 + r;
#pragma unroll
    for (int nd = 0; nd < 4; ++nd)
      outp[(size_t)q * DMODEL + nd * 16 + c] = f2bf(aco[nd][r] * inv);
  }
}

extern "C" void kernel_launch(void* const* d_in, const int* in_sizes, int n_in,
                              void* d_out, int out_size, void* d_ws, size_t ws_size,
                              hipStream_t stream) {
  const float* x = (const float*)d_in[0];
  const float* nw = (const float*)d_in[1];
  const float* qkv_w = (const float*)d_in[2];
  const float* out_w = (const float*)d_in[3];
  float* out = (float*)d_out;

  unsigned short* ws = (unsigned short*)d_ws;
  unsigned short* xn = ws;
  unsigned short* qkvw = xn + (size_t)MROWS * DMODEL;
  unsigned short* outw = qkvw + (size_t)3 * DMODEL * DMODEL;
  unsigned short* qkv = outw + (size_t)DMODEL * DMODEL;
  unsigned short* ctx = qkv + (size_t)MROWS * 3 * DMODEL;

  cvt_all<<<dim3(4096), dim3(256), 0, stream>>>(qkv_w, out_w, qkvw);
  rmsnorm_bf16<<<dim3(MROWS), dim3(256), 0, stream>>>(x, nw, xn);
  gemm_bt<0><<<dim3(768), dim3(256), 0, stream>>>(xn, qkvw, qkv, MROWS, 3 * DMODEL, DMODEL, 24);
  attn_causal<<<dim3(1024), dim3(256), 0, stream>>>(qkv, ctx);
  gemm_bt<1><<<dim3(256), dim3(256), 0, stream>>>(ctx, outw, out, MROWS, DMODEL, DMODEL, 8);
}

// Round 11
// 122.099 us; speedup vs baseline: 1.3530x; 1.0908x over previous
//
#include <hip/hip_runtime.h>
#include <stdint.h>

#define B_SZ 2
#define T_SZ 2048
#define DMODEL 1024
#define HCNT 16
#define HD 64
#define MROWS (B_SZ * T_SZ)  // 4096

typedef __attribute__((ext_vector_type(8))) __bf16 bf16x8;
typedef __attribute__((ext_vector_type(4))) __bf16 bf16x4;
typedef __attribute__((ext_vector_type(4))) float f32x4;
typedef __attribute__((ext_vector_type(8))) unsigned short u16x8;

__device__ __forceinline__ unsigned short f2bf(float f) {
  union { float f; uint32_t u; } v; v.f = f;
  uint32_t u = v.u;
  u += 0x7fffu + ((u >> 16) & 1u);
  return (unsigned short)(u >> 16);
}

__device__ __forceinline__ float fexp2(float x) {
#if __has_builtin(__builtin_amdgcn_exp2f)
  return __builtin_amdgcn_exp2f(x);
#else
  return exp2f(x);
#endif
}

__device__ __forceinline__ void gld_lds16(const void* g, void* l) {
  __builtin_amdgcn_global_load_lds((__attribute__((address_space(1))) void*)(uintptr_t)g,
                                   (__attribute__((address_space(3))) void*)l, 16, 0, 0);
}

// ---------------- fp32 -> bf16 convert (both weight tensors, one launch) ----
__global__ __launch_bounds__(256)
void cvt_all(const float* __restrict__ qkv_w, const float* __restrict__ out_w,
             unsigned short* __restrict__ dst) {
  int i = blockIdx.x * 256 + threadIdx.x;
  const int n1 = 3 * DMODEL * DMODEL / 4;
  float4 v = (i < n1) ? ((const float4*)qkv_w)[i] : ((const float4*)out_w)[i - n1];
  ushort4 o;
  o.x = f2bf(v.x); o.y = f2bf(v.y); o.z = f2bf(v.z); o.w = f2bf(v.w);
  ((ushort4*)dst)[i] = o;
}

// ---------------- RMSNorm (fp32 in, bf16 out) ----------------
__global__ __launch_bounds__(256)
void rmsnorm_bf16(const float* __restrict__ x, const float* __restrict__ w,
                  unsigned short* __restrict__ xn) {
  const int row = blockIdx.x;
  const int t = threadIdx.x;
  float4 v = ((const float4*)(x + (size_t)row * DMODEL))[t];
  float ss = v.x * v.x + v.y * v.y + v.z * v.z + v.w * v.w;
#pragma unroll
  for (int o = 1; o < 64; o <<= 1) ss += __shfl_xor(ss, o, 64);
  __shared__ float red[4];
  if ((t & 63) == 0) red[t >> 6] = ss;
  __syncthreads();
  float tot = red[0] + red[1] + red[2] + red[3];
  float scale = rsqrtf(tot * (1.0f / (float)DMODEL) + 1e-6f);
  float4 wv = ((const float4*)w)[t];
  ushort4 o;
  o.x = f2bf(v.x * scale * wv.x);
  o.y = f2bf(v.y * scale * wv.y);
  o.z = f2bf(v.z * scale * wv.z);
  o.w = f2bf(v.w * scale * wv.w);
  ((ushort4*)(xn + (size_t)row * DMODEL))[t] = o;
}

// ---------------- bf16 NT GEMM: C[M][N] = A[M][K] * B[N][K]^T, BK=64 --------
// T2 XOR-swizzle (source pre-swizzled, LDS linear, read XORs the same).
__device__ __forceinline__ void stage128x64(const unsigned short* g, int ldg,
                                            unsigned short* lds, int tid) {
  const int wave = tid >> 6;
#pragma unroll
  for (int i = 0; i < 4; ++i) {
    int row = i * 32 + (tid >> 3);
    const unsigned short* gp = g + (size_t)row * ldg + (((tid & 7) ^ (row & 7)) << 3);
    gld_lds16(gp, lds + i * 2048 + wave * 512);
  }
}

template <int F32OUT>
__global__ __launch_bounds__(256, 2)
void gemm_bt(const unsigned short* __restrict__ A, const unsigned short* __restrict__ B,
             void* __restrict__ Cv, int M, int N, int K, int nbx) {
  __shared__ __align__(16) unsigned short As[2][128 * 64];
  __shared__ __align__(16) unsigned short Bs[2][128 * 64];
  const int t = threadIdx.x, wave = t >> 6, lane = t & 63;
  const int cpx = gridDim.x >> 3;
  const int swz = (blockIdx.x & 7) * cpx + (blockIdx.x >> 3);
  const int m0 = (swz / nbx) * 128, n0 = (swz % nbx) * 128;
  const int wr = wave >> 1, wc = wave & 1;
  const int c = lane & 15, qg = lane >> 4;
  f32x4 acc[4][4] = {};
  const int nk = K >> 6;
  stage128x64(A + (size_t)m0 * K, K, As[0], t);
  stage128x64(B + (size_t)n0 * K, K, Bs[0], t);
  __syncthreads();
  int buf = 0;
  for (int kt = 0; kt < nk; ++kt) {
    if (kt + 1 < nk) {
      stage128x64(A + (size_t)m0 * K + (kt + 1) * 64, K, As[buf ^ 1], t);
      stage128x64(B + (size_t)n0 * K + (kt + 1) * 64, K, Bs[buf ^ 1], t);
    }
#pragma unroll
    for (int kk = 0; kk < 2; ++kk) {
      bf16x8 af[4], bfr[4];
#pragma unroll
      for (int mi = 0; mi < 4; ++mi) {
        int row = wr * 64 + mi * 16 + c;
        af[mi] = *(const bf16x8*)&As[buf][row * 64 + (((kk * 4 + qg) ^ (row & 7)) << 3)];
      }
#pragma unroll
      for (int ni = 0; ni < 4; ++ni) {
        int row = wc * 64 + ni * 16 + c;
        bfr[ni] = *(const bf16x8*)&Bs[buf][row * 64 + (((kk * 4 + qg) ^ (row & 7)) << 3)];
      }
#pragma unroll
      for (int mi = 0; mi < 4; ++mi)
#pragma unroll
        for (int ni = 0; ni < 4; ++ni)
          acc[mi][ni] = __builtin_amdgcn_mfma_f32_16x16x32_bf16(af[mi], bfr[ni], acc[mi][ni], 0, 0, 0);
    }
    __syncthreads();
    buf ^= 1;
  }
  const int cr = qg * 4;
#pragma unroll
  for (int mi = 0; mi < 4; ++mi)
#pragma unroll
    for (int ni = 0; ni < 4; ++ni) {
      int row = m0 + wr * 64 + mi * 16 + cr;
      int col = n0 + wc * 64 + ni * 16 + c;
      if (F32OUT) {
        float* C = (float*)Cv;
#pragma unroll
        for (int r = 0; r < 4; ++r) C[(size_t)(row + r) * N + col] = acc[mi][ni][r];
      } else {
        unsigned short* C = (unsigned short*)Cv;
#pragma unroll
        for (int r = 0; r < 4; ++r) C[(size_t)(row + r) * N + col] = f2bf(acc[mi][ni][r]);
      }
    }
}

// ---------------- causal flash attention v10: paired halves, 2 groups/CU ----
// 512 blocks x 256 thr (4 waves). Block (bh, p, half) = one 64-row half of
// q-tiles p (small) and 15-p (big); each wave owns 16 rows of each (mi=0/1)
// sharing ONE K/V stream of nit=16-p KVBLK=128 tiles; uniform 17 work-units.
// Co-resident CU pair gets (ph, 7-ph) -> uniform per-CU work. LDS 79.1 KB ->
// 2 blocks/CU = two INDEPENDENT 4-wave barrier groups (v5 had one 8-wave
// convoy). launch_bounds(256,2) = v5's no-spill allocator contract (VGPR~110).
// K dbuf gld_lds; V dbuf reg-staged (T14: load before compute, write after);
// paired P-strip (v8-validated layout); one barrier per k-tile.
__global__ __launch_bounds__(256, 2)
void attn_causal(const unsigned short* __restrict__ qkv, unsigned short* __restrict__ ctx) {
  __shared__ __align__(16) unsigned short Ks[2][128 * 64];     // 32 KB
  __shared__ __align__(16) unsigned short Vt[2][2][64 * 72];   // 36.9 KB
  __shared__ __align__(16) unsigned short Pl[4][32 * 40];      // 10.2 KB
  const int tid = threadIdx.x, wave = tid >> 6, lane = tid & 63;
  const int id = blockIdx.x;
  const int bh = id & 31;                    // id%8 = bh%8 -> XCD pinned
  const int ph = (id >> 5) & 7;
  const int half = (id >> 8) & 1;
  const int p = half ? 7 - ph : ph;          // co-resident CU pair: (ph, 7-ph)
  const int b = bh >> 4, h = bh & 15;
  const int q0a = p * 128 + half * 64 + wave * 16;          // small tile rows
  const int q0b = (15 - p) * 128 + half * 64 + wave * 16;   // big tile rows
  const int nit = 16 - p;
  const int c = lane & 15, qg = lane >> 4;
  const size_t base = (size_t)b * T_SZ * 3 * DMODEL;
  const unsigned short* Kg = qkv + base + DMODEL + h * HD;
  const unsigned short* Vg = qkv + base + 2 * DMODEL + h * HD;

  // Q fragments, pre-scaled by 0.125 * log2(e)
  const float QSC = 0.125f * 1.4426950408889634f;
  bf16x8 aq[2][2];
#pragma unroll
  for (int mi = 0; mi < 2; ++mi)
#pragma unroll
    for (int kk = 0; kk < 2; ++kk) {
      int q = (mi ? q0b : q0a) + c;
      bf16x8 fq = *(const bf16x8*)(qkv + base + (size_t)q * 3 * DMODEL + h * HD + kk * 32 + qg * 8);
#pragma unroll
      for (int j = 0; j < 8; ++j) fq[j] = (__bf16)((float)fq[j] * QSC);
      aq[mi][kk] = fq;
    }

  float mst[2] = {-3e38f, -3e38f}, lst[2] = {0.f, 0.f};
  f32x4 aco[2][4];
#pragma unroll
  for (int mi = 0; mi < 2; ++mi)
#pragma unroll
    for (int nd = 0; nd < 4; ++nd)
#pragma unroll
      for (int r = 0; r < 4; ++r) aco[mi][nd][r] = 0.f;

  auto stageK = [&](int kb, int bufi) {
#pragma unroll
    for (int i = 0; i < 4; ++i) {
      int row = i * 32 + (tid >> 3);
      gld_lds16(Kg + (size_t)(kb + row) * 3 * DMODEL + (((tid & 7) ^ (row & 7)) << 3),
                &Ks[bufi][i * 2048 + (wave << 9)]);
    }
  };
  auto loadV = [&](int kb, u16x8* v) {
#pragma unroll
    for (int i = 0; i < 4; ++i)
      v[i] = *(const u16x8*)(Vg + (size_t)(kb + i * 32 + (tid >> 3)) * 3 * DMODEL + (tid & 7) * 8);
  };
  auto writeV = [&](int bufi, const u16x8* v) {
#pragma unroll
    for (int i = 0; i < 4; ++i) {
      int ch = i >> 1;
      int kv = (i & 1) * 32 + (tid >> 3);
#pragma unroll
      for (int j = 0; j < 8; ++j) {
        int dd = (tid & 7) * 8 + j;
        int ff = (tid & 7) ^ j;      // ((dd>>3)^dd)&7
        Vt[bufi][ch][dd * 72 + ((((kv >> 3) ^ ff) << 3) | (kv & 7))] = v[i][j];
      }
    }
  };

  auto softmaxRow = [&](int mi, f32x4 (&s)[8][2]) {
    float rm = -3e38f;
#pragma unroll
    for (int ni = 0; ni < 8; ++ni)
#pragma unroll
      for (int r = 0; r < 4; ++r) rm = fmaxf(rm, s[ni][mi][r]);
    rm = fmaxf(rm, __shfl_xor(rm, 16, 64));
    rm = fmaxf(rm, __shfl_xor(rm, 32, 64));
    float mo = mst[mi];
    float mn = mo;
    if (__any(rm > mo + 11.5f)) {
      mn = fmaxf(mo, rm);
      float corr = fexp2(mo - mn);
      lst[mi] *= corr;
      mst[mi] = mn;
#pragma unroll
      for (int r = 0; r < 4; ++r) {
        float cr = __shfl(corr, qg * 20 + r, 64);
#pragma unroll
        for (int nd = 0; nd < 4; ++nd) aco[mi][nd][r] *= cr;
      }
    }
    float rs = 0.f;
#pragma unroll
    for (int ni = 0; ni < 8; ++ni)
#pragma unroll
      for (int r = 0; r < 4; ++r) {
        float pv = fexp2(s[ni][mi][r] - mn);
        s[ni][mi][r] = pv;
        rs += pv;
      }
    rs += __shfl_xor(rs, 16, 64);
    rs += __shfl_xor(rs, 32, 64);
    lst[mi] += rs;
  };

  auto computeTile = [&](int kb, int kbuf, bool both, bool maskA, bool maskB) {
    f32x4 s[8][2] = {};
    __builtin_amdgcn_s_setprio(1);
#pragma unroll
    for (int kk = 0; kk < 2; ++kk) {
      bf16x8 bk[8];
#pragma unroll
      for (int ni = 0; ni < 8; ++ni) {
        int row = ni * 16 + c;
        int crd = kk * 4 + qg;
        bk[ni] = *(const bf16x8*)&Ks[kbuf][row * 64 + ((crd ^ (row & 7)) << 3)];
      }
#pragma unroll
      for (int ni = 0; ni < 8; ++ni)
        s[ni][1] = __builtin_amdgcn_mfma_f32_16x16x32_bf16(bk[ni], aq[1][kk], s[ni][1], 0, 0, 0);
      if (both)
#pragma unroll
        for (int ni = 0; ni < 8; ++ni)
          s[ni][0] = __builtin_amdgcn_mfma_f32_16x16x32_bf16(bk[ni], aq[0][kk], s[ni][0], 0, 0, 0);
    }
    __builtin_amdgcn_s_setprio(0);
    if (maskB) {
#pragma unroll
      for (int ni = 0; ni < 8; ++ni)
#pragma unroll
        for (int r = 0; r < 4; ++r) {
          int kg = kb + ni * 16 + qg * 4 + r;
          if (kg > q0b + c) s[ni][1][r] = -1e30f;
        }
    }
    if (both && maskA) {
#pragma unroll
      for (int ni = 0; ni < 8; ++ni)
#pragma unroll
        for (int r = 0; r < 4; ++r) {
          int kg = kb + ni * 16 + qg * 4 + r;
          if (kg > q0a + c) s[ni][0][r] = -1e30f;
        }
    }
    softmaxRow(1, s);
    if (both) softmaxRow(0, s);
    // PV via per-wave P-strip [32 x 40] (rows: c = tile A, 16+c = tile B),
    // strip col == kv offset within the current 32-block; reused per (ch,kk).
    unsigned short* P = Pl[wave];
    __builtin_amdgcn_s_setprio(1);
#pragma unroll
    for (int ch = 0; ch < 2; ++ch)
#pragma unroll
      for (int kk = 0; kk < 2; ++kk) {
#pragma unroll
        for (int par = 0; par < 2; ++par) {
          int ni = ch * 4 + kk * 2 + par;
          bf16x4 pkB;
#pragma unroll
          for (int r = 0; r < 4; ++r) pkB[r] = (__bf16)s[ni][1][r];
          *(bf16x4*)&P[(16 + c) * 40 + par * 16 + qg * 4] = pkB;
          if (both) {
            bf16x4 pkA;
#pragma unroll
            for (int r = 0; r < 4; ++r) pkA[r] = (__bf16)s[ni][0][r];
            *(bf16x4*)&P[c * 40 + par * 16 + qg * 4] = pkA;
          }
        }
        bf16x8 bv[4];
#pragma unroll
        for (int nd = 0; nd < 4; ++nd) {
          int dd = nd * 16 + c;
          int ff = ((dd >> 3) ^ dd) & 7;
          int crd = kk * 4 + qg;
          bv[nd] = *(const bf16x8*)&Vt[kbuf][ch][dd * 72 + ((crd ^ ff) << 3)];
        }
        bf16x8 paB = *(const bf16x8*)&P[(16 + c) * 40 + qg * 8];
#pragma unroll
        for (int nd = 0; nd < 4; ++nd)
          aco[1][nd] = __builtin_amdgcn_mfma_f32_16x16x32_bf16(paB, bv[nd], aco[1][nd], 0, 0, 0);
        if (both) {
          bf16x8 paA = *(const bf16x8*)&P[c * 40 + qg * 8];
#pragma unroll
          for (int nd = 0; nd < 4; ++nd)
            aco[0][nd] = __builtin_amdgcn_mfma_f32_16x16x32_bf16(paA, bv[nd], aco[0][nd], 0, 0, 0);
        }
      }
    __builtin_amdgcn_s_setprio(0);
  };

  // prologue: tile 0
  stageK(0, 0);
  {
    u16x8 v0[4];
    loadV(0, v0);
    writeV(0, v0);
  }
  __syncthreads();
  int kbuf = 0;
  for (int t = 0; t < nit; ++t) {
    const int kb = t * 128;
    const bool hn = (t + 1 < nit);
    u16x8 vn[4];
    if (hn) { stageK(kb + 128, kbuf ^ 1); loadV(kb + 128, vn); }
    computeTile(kb, kbuf, t <= p, t == p, t == nit - 1);
    if (hn) writeV(kbuf ^ 1, vn);
    __syncthreads();
    kbuf ^= 1;
  }

  // epilogue: O /= l
  unsigned short* outp = ctx + (size_t)b * T_SZ * DMODEL + h * HD;
#pragma unroll
  for (int mi = 0; mi < 2; ++mi) {
    float linv = 1.f / lst[mi];
#pragma unroll
    for (int r = 0; r < 4; ++r) {
      float inv = __shfl(linv, qg * 20 + r, 64);
      int q = (mi ? q0b : q0a) + qg * 4 + r;
#pragma unroll
      for (int nd = 0; nd < 4; ++nd)
        outp[(size_t)q * DMODEL + nd * 16 + c] = f2bf(aco[mi][nd][r] * inv);
    }
  }
}

extern "C" void kernel_launch(void* const* d_in, const int* in_sizes, int n_in,
                              void* d_out, int out_size, void* d_ws, size_t ws_size,
                              hipStream_t stream) {
  const float* x = (const float*)d_in[0];
  const float* nw = (const float*)d_in[1];
  const float* qkv_w = (const float*)d_in[2];
  const float* out_w = (const float*)d_in[3];
  float* out = (float*)d_out;

  unsigned short* ws = (unsigned short*)d_ws;
  unsigned short* xn = ws;
  unsigned short* qkvw = xn + (size_t)MROWS * DMODEL;
  unsigned short* outw = qkvw + (size_t)3 * DMODEL * DMODEL;
  unsigned short* qkv = outw + (size_t)DMODEL * DMODEL;
  unsigned short* ctx = qkv + (size_t)MROWS * 3 * DMODEL;

  cvt_all<<<dim3(4096), dim3(256), 0, stream>>>(qkv_w, out_w, qkvw);
  rmsnorm_bf16<<<dim3(MROWS), dim3(256), 0, stream>>>(x, nw, xn);
  gemm_bt<0><<<dim3(768), dim3(256), 0, stream>>>(xn, qkvw, qkv, MROWS, 3 * DMODEL, DMODEL, 24);
  attn_causal<<<dim3(512), dim3(256), 0, stream>>>(qkv, ctx);
  gemm_bt<1><<<dim3(256), dim3(256), 0, stream>>>(ctx, outw, out, MROWS, DMODEL, DMODEL, 8);
}

// Round 12
// 121.803 us; speedup vs baseline: 1.3563x; 1.0024x over previous
//
#include <hip/hip_runtime.h>
#include <stdint.h>

#define B_SZ 2
#define T_SZ 2048
#define DMODEL 1024
#define HCNT 16
#define HD 64
#define MROWS (B_SZ * T_SZ)  // 4096

typedef __attribute__((ext_vector_type(8))) __bf16 bf16x8;
typedef __attribute__((ext_vector_type(4))) __bf16 bf16x4;
typedef __attribute__((ext_vector_type(4))) float f32x4;
typedef __attribute__((ext_vector_type(8))) unsigned short u16x8;

__device__ __forceinline__ unsigned short f2bf(float f) {
  union { float f; uint32_t u; } v; v.f = f;
  uint32_t u = v.u;
  u += 0x7fffu + ((u >> 16) & 1u);
  return (unsigned short)(u >> 16);
}

__device__ __forceinline__ float fexp2(float x) {
#if __has_builtin(__builtin_amdgcn_exp2f)
  return __builtin_amdgcn_exp2f(x);
#else
  return exp2f(x);
#endif
}

__device__ __forceinline__ void gld_lds16(const void* g, void* l) {
  __builtin_amdgcn_global_load_lds((__attribute__((address_space(1))) void*)(uintptr_t)g,
                                   (__attribute__((address_space(3))) void*)l, 16, 0, 0);
}

// ---------------- fp32 -> bf16 convert (both weight tensors, one launch) ----
__global__ __launch_bounds__(256)
void cvt_all(const float* __restrict__ qkv_w, const float* __restrict__ out_w,
             unsigned short* __restrict__ dst) {
  int i = blockIdx.x * 256 + threadIdx.x;
  const int n1 = 3 * DMODEL * DMODEL / 4;
  float4 v = (i < n1) ? ((const float4*)qkv_w)[i] : ((const float4*)out_w)[i - n1];
  ushort4 o;
  o.x = f2bf(v.x); o.y = f2bf(v.y); o.z = f2bf(v.z); o.w = f2bf(v.w);
  ((ushort4*)dst)[i] = o;
}

// ---------------- RMSNorm (fp32 in, bf16 out) ----------------
__global__ __launch_bounds__(256)
void rmsnorm_bf16(const float* __restrict__ x, const float* __restrict__ w,
                  unsigned short* __restrict__ xn) {
  const int row = blockIdx.x;
  const int t = threadIdx.x;
  float4 v = ((const float4*)(x + (size_t)row * DMODEL))[t];
  float ss = v.x * v.x + v.y * v.y + v.z * v.z + v.w * v.w;
#pragma unroll
  for (int o = 1; o < 64; o <<= 1) ss += __shfl_xor(ss, o, 64);
  __shared__ float red[4];
  if ((t & 63) == 0) red[t >> 6] = ss;
  __syncthreads();
  float tot = red[0] + red[1] + red[2] + red[3];
  float scale = rsqrtf(tot * (1.0f / (float)DMODEL) + 1e-6f);
  float4 wv = ((const float4*)w)[t];
  ushort4 o;
  o.x = f2bf(v.x * scale * wv.x);
  o.y = f2bf(v.y * scale * wv.y);
  o.z = f2bf(v.z * scale * wv.z);
  o.w = f2bf(v.w * scale * wv.w);
  ((ushort4*)(xn + (size_t)row * DMODEL))[t] = o;
}

// ---------------- bf16 NT GEMM: C[M][N] = A[M][K] * B[N][K]^T, BK=64 --------
// T2 XOR-swizzle (source pre-swizzled, LDS linear, read XORs the same).
__device__ __forceinline__ void stage128x64(const unsigned short* g, int ldg,
                                            unsigned short* lds, int tid) {
  const int wave = tid >> 6;
#pragma unroll
  for (int i = 0; i < 4; ++i) {
    int row = i * 32 + (tid >> 3);
    const unsigned short* gp = g + (size_t)row * ldg + (((tid & 7) ^ (row & 7)) << 3);
    gld_lds16(gp, lds + i * 2048 + wave * 512);
  }
}

template <int F32OUT>
__global__ __launch_bounds__(256, 2)
void gemm_bt(const unsigned short* __restrict__ A, const unsigned short* __restrict__ B,
             void* __restrict__ Cv, int M, int N, int K, int nbx) {
  __shared__ __align__(16) unsigned short As[2][128 * 64];
  __shared__ __align__(16) unsigned short Bs[2][128 * 64];
  const int t = threadIdx.x, wave = t >> 6, lane = t & 63;
  const int cpx = gridDim.x >> 3;
  const int swz = (blockIdx.x & 7) * cpx + (blockIdx.x >> 3);
  const int m0 = (swz / nbx) * 128, n0 = (swz % nbx) * 128;
  const int wr = wave >> 1, wc = wave & 1;
  const int c = lane & 15, qg = lane >> 4;
  f32x4 acc[4][4] = {};
  const int nk = K >> 6;
  stage128x64(A + (size_t)m0 * K, K, As[0], t);
  stage128x64(B + (size_t)n0 * K, K, Bs[0], t);
  __syncthreads();
  int buf = 0;
  for (int kt = 0; kt < nk; ++kt) {
    if (kt + 1 < nk) {
      stage128x64(A + (size_t)m0 * K + (kt + 1) * 64, K, As[buf ^ 1], t);
      stage128x64(B + (size_t)n0 * K + (kt + 1) * 64, K, Bs[buf ^ 1], t);
    }
#pragma unroll
    for (int kk = 0; kk < 2; ++kk) {
      bf16x8 af[4], bfr[4];
#pragma unroll
      for (int mi = 0; mi < 4; ++mi) {
        int row = wr * 64 + mi * 16 + c;
        af[mi] = *(const bf16x8*)&As[buf][row * 64 + (((kk * 4 + qg) ^ (row & 7)) << 3)];
      }
#pragma unroll
      for (int ni = 0; ni < 4; ++ni) {
        int row = wc * 64 + ni * 16 + c;
        bfr[ni] = *(const bf16x8*)&Bs[buf][row * 64 + (((kk * 4 + qg) ^ (row & 7)) << 3)];
      }
#pragma unroll
      for (int mi = 0; mi < 4; ++mi)
#pragma unroll
        for (int ni = 0; ni < 4; ++ni)
          acc[mi][ni] = __builtin_amdgcn_mfma_f32_16x16x32_bf16(af[mi], bfr[ni], acc[mi][ni], 0, 0, 0);
    }
    __syncthreads();
    buf ^= 1;
  }
  const int cr = qg * 4;
#pragma unroll
  for (int mi = 0; mi < 4; ++mi)
#pragma unroll
    for (int ni = 0; ni < 4; ++ni) {
      int row = m0 + wr * 64 + mi * 16 + cr;
      int col = n0 + wc * 64 + ni * 16 + c;
      if (F32OUT) {
        float* C = (float*)Cv;
#pragma unroll
        for (int r = 0; r < 4; ++r) C[(size_t)(row + r) * N + col] = acc[mi][ni][r];
      } else {
        unsigned short* C = (unsigned short*)Cv;
#pragma unroll
        for (int r = 0; r < 4; ++r) C[(size_t)(row + r) * N + col] = f2bf(acc[mi][ni][r]);
      }
    }
}

// ---------------- causal flash attention v11: uniform sequential pairs ------
// 512 blocks x 256 thr (4 waves x 16 rows = 64-row strip). Block (bh,p,half)
// runs TWO single-tile phases sequentially: q-tile 15-p (16-p k-tiles) then
// q-tile p (p+1 k-tiles) -> EVERY block = exactly 17 KVBLK=128 iterations,
// so all 512 co-resident blocks (2/CU) finish together (v10's (16-p,9+p)
// pairing wasted ~25% of wave-slots). K dbuf gld_lds, V dbuf reg-staged (T14).
// Softmax denominator via MFMA row-sum (ones B-fragment) -> kills 32 VALU
// adds + 2 shfls per tile and lands in aco's layout (no epilogue shfl).
__global__ __launch_bounds__(256, 2)
void attn_causal(const unsigned short* __restrict__ qkv, unsigned short* __restrict__ ctx) {
  __shared__ __align__(16) unsigned short Ks[2][128 * 64];     // 32 KB
  __shared__ __align__(16) unsigned short Vt[2][2][64 * 72];   // 36.9 KB
  __shared__ __align__(16) unsigned short Pl[4][16 * 40];      // 5.1 KB
  const int tid = threadIdx.x, wave = tid >> 6, lane = tid & 63;
  const int id = blockIdx.x;
  const int bh = id & 31;                    // id%8 = bh%8 -> XCD pinned
  const int pr = id >> 5;                    // 0..15
  const int p = pr & 7, half = pr >> 3;
  const int b = bh >> 4, h = bh & 15;
  const int c = lane & 15, qg = lane >> 4;
  const size_t base = (size_t)b * T_SZ * 3 * DMODEL;
  const unsigned short* Kg = qkv + base + DMODEL + h * HD;
  const unsigned short* Vg = qkv + base + 2 * DMODEL + h * HD;
  unsigned short* outp = ctx + (size_t)b * T_SZ * DMODEL + h * HD;

  const float QSC = 0.125f * 1.4426950408889634f;
  bf16x8 ones;
#pragma unroll
  for (int j = 0; j < 8; ++j) ones[j] = (__bf16)1.0f;

  auto stageK = [&](int kb, int bufi) {
#pragma unroll
    for (int i = 0; i < 4; ++i) {
      int row = i * 32 + (tid >> 3);
      gld_lds16(Kg + (size_t)(kb + row) * 3 * DMODEL + (((tid & 7) ^ (row & 7)) << 3),
                &Ks[bufi][i * 2048 + (wave << 9)]);
    }
  };
  auto loadV = [&](int kb, u16x8* v) {
#pragma unroll
    for (int i = 0; i < 4; ++i)
      v[i] = *(const u16x8*)(Vg + (size_t)(kb + i * 32 + (tid >> 3)) * 3 * DMODEL + (tid & 7) * 8);
  };
  auto writeV = [&](int bufi, const u16x8* v) {
#pragma unroll
    for (int i = 0; i < 4; ++i) {
      int ch = i >> 1;
      int kv = (i & 1) * 32 + (tid >> 3);
#pragma unroll
      for (int j = 0; j < 8; ++j) {
        int dd = (tid & 7) * 8 + j;
        int ff = (tid & 7) ^ j;      // ((dd>>3)^dd)&7
        Vt[bufi][ch][dd * 72 + ((((kv >> 3) ^ ff) << 3) | (kv & 7))] = v[i][j];
      }
    }
  };

  // ---- one single-tile flash phase over q-tile qt (nit = qt+1 k-tiles) ----
  auto runPhase = [&](int qt) {
    const int q0 = qt * 128 + half * 64 + wave * 16;
    const int nit = qt + 1;
    // Q fragments, pre-scaled
    bf16x8 aq[2];
#pragma unroll
    for (int kk = 0; kk < 2; ++kk) {
      bf16x8 q = *(const bf16x8*)(qkv + base + (size_t)(q0 + c) * 3 * DMODEL + h * HD + kk * 32 + qg * 8);
#pragma unroll
      for (int j = 0; j < 8; ++j) q[j] = (__bf16)((float)q[j] * QSC);
      aq[kk] = q;
    }
    float mst = -3e38f;
    f32x4 aco[4] = {};
    f32x4 acs = {};        // MFMA row-sum accumulator (softmax denominator)
    u16x8 vn[4];
    stageK(0, 0);
    loadV(0, vn);
    writeV(0, vn);
    __syncthreads();
    int kbuf = 0;
    for (int t = 0; t < nit; ++t) {
      const int kb = t * 128;
      const bool hn = (t + 1 < nit);
      if (hn) { stageK(kb + 128, kbuf ^ 1); loadV(kb + 128, vn); }
      // S^T = K Q^T : s[ni], k-row = kb + 16ni + 4qg + r, q-col = q0 + c
      f32x4 s[8] = {};
      __builtin_amdgcn_s_setprio(1);
#pragma unroll
      for (int kk = 0; kk < 2; ++kk) {
        bf16x8 bk[8];
#pragma unroll
        for (int ni = 0; ni < 8; ++ni) {
          int row = ni * 16 + c;
          int crd = kk * 4 + qg;
          bk[ni] = *(const bf16x8*)&Ks[kbuf][row * 64 + ((crd ^ (row & 7)) << 3)];
        }
#pragma unroll
        for (int ni = 0; ni < 8; ++ni)
          s[ni] = __builtin_amdgcn_mfma_f32_16x16x32_bf16(bk[ni], aq[kk], s[ni], 0, 0, 0);
      }
      __builtin_amdgcn_s_setprio(0);
      if (t == nit - 1) {  // diagonal tile: causal mask
#pragma unroll
        for (int ni = 0; ni < 8; ++ni)
#pragma unroll
          for (int r = 0; r < 4; ++r) {
            int kg = kb + ni * 16 + qg * 4 + r;
            if (kg > q0 + c) s[ni][r] = -1e30f;
          }
      }
      // online softmax (log2 domain), defer-max; row q0+c stats lane-local
      float rm = -3e38f;
#pragma unroll
      for (int ni = 0; ni < 8; ++ni)
#pragma unroll
        for (int r = 0; r < 4; ++r) rm = fmaxf(rm, s[ni][r]);
      rm = fmaxf(rm, __shfl_xor(rm, 16, 64));
      rm = fmaxf(rm, __shfl_xor(rm, 32, 64));
      float mn = mst;
      if (__any(rm > mst + 11.5f)) {
        mn = fmaxf(mst, rm);
        float corr = fexp2(mst - mn);
        mst = mn;
#pragma unroll
        for (int r = 0; r < 4; ++r) {
          float cr = __shfl(corr, qg * 20 + r, 64);   // corr of row 4qg+r
          acs[r] *= cr;
#pragma unroll
          for (int nd = 0; nd < 4; ++nd) aco[nd][r] *= cr;
        }
      }
#pragma unroll
      for (int ni = 0; ni < 8; ++ni)
#pragma unroll
        for (int r = 0; r < 4; ++r) s[ni][r] = fexp2(s[ni][r] - mn);
      // PV per 32-col slice via per-wave P strip; denominator via ones-MFMA
      unsigned short* P = Pl[wave];
      __builtin_amdgcn_s_setprio(1);
#pragma unroll
      for (int ch = 0; ch < 2; ++ch)
#pragma unroll
        for (int kk = 0; kk < 2; ++kk) {
#pragma unroll
          for (int par = 0; par < 2; ++par) {
            int ni = ch * 4 + kk * 2 + par;
            bf16x4 pk;
#pragma unroll
            for (int r = 0; r < 4; ++r) pk[r] = (__bf16)s[ni][r];
            *(bf16x4*)&P[c * 40 + par * 16 + qg * 4] = pk;
          }
          bf16x8 pa = *(const bf16x8*)&P[c * 40 + qg * 8];
          bf16x8 bv[4];
#pragma unroll
          for (int nd = 0; nd < 4; ++nd) {
            int dd = nd * 16 + c;
            int ff = ((dd >> 3) ^ dd) & 7;
            int crd = kk * 4 + qg;
            bv[nd] = *(const bf16x8*)&Vt[kbuf][ch][dd * 72 + ((crd ^ ff) << 3)];
          }
#pragma unroll
          for (int nd = 0; nd < 4; ++nd)
            aco[nd] = __builtin_amdgcn_mfma_f32_16x16x32_bf16(pa, bv[nd], aco[nd], 0, 0, 0);
          acs = __builtin_amdgcn_mfma_f32_16x16x32_bf16(pa, ones, acs, 0, 0, 0);
        }
      __builtin_amdgcn_s_setprio(0);
      if (hn) writeV(kbuf ^ 1, vn);
      __syncthreads();
      kbuf ^= 1;
    }
    // epilogue: O /= l (acs already in aco's row layout: row = q0 + 4qg + r)
#pragma unroll
    for (int r = 0; r < 4; ++r) {
      float inv = 1.f / acs[r];
      int q = q0 + qg * 4 + r;
#pragma unroll
      for (int nd = 0; nd < 4; ++nd)
        outp[(size_t)q * DMODEL + nd * 16 + c] = f2bf(aco[nd][r] * inv);
    }
  };

  runPhase(15 - p);   // big tile first
  __syncthreads();    // protect Ks/Vt before phase 2 restages
  runPhase(p);        // small tile; total = 17 k-tile iterations for ALL blocks
}

extern "C" void kernel_launch(void* const* d_in, const int* in_sizes, int n_in,
                              void* d_out, int out_size, void* d_ws, size_t ws_size,
                              hipStream_t stream) {
  const float* x = (const float*)d_in[0];
  const float* nw = (const float*)d_in[1];
  const float* qkv_w = (const float*)d_in[2];
  const float* out_w = (const float*)d_in[3];
  float* out = (float*)d_out;

  unsigned short* ws = (unsigned short*)d_ws;
  unsigned short* xn = ws;
  unsigned short* qkvw = xn + (size_t)MROWS * DMODEL;
  unsigned short* outw = qkvw + (size_t)3 * DMODEL * DMODEL;
  unsigned short* qkv = outw + (size_t)DMODEL * DMODEL;
  unsigned short* ctx = qkv + (size_t)MROWS * 3 * DMODEL;

  cvt_all<<<dim3(4096), dim3(256), 0, stream>>>(qkv_w, out_w, qkvw);
  rmsnorm_bf16<<<dim3(MROWS), dim3(256), 0, stream>>>(x, nw, xn);
  gemm_bt<0><<<dim3(768), dim3(256), 0, stream>>>(xn, qkvw, qkv, MROWS, 3 * DMODEL, DMODEL, 24);
  attn_causal<<<dim3(512), dim3(256), 0, stream>>>(qkv, ctx);
  gemm_bt<1><<<dim3(256), dim3(256), 0, stream>>>(ctx, outw, out, MROWS, DMODEL, DMODEL, 8);
}